// Round 15
// baseline (268.734 us; speedup 1.0000x reference)
//
#include <hip/hip_runtime.h>
#include <hip/hip_bf16.h>

// Problem constants (shapes fixed by the reference)
#define XS   2
#define NP   96
#define NLAY 3
#define NXI  (XS*NP)   // 192
// L_INPUT = 3, DIMS = (1,3,5,7), MAX_DIM = 7, NUM_CG = 4, NUM_CH = 16

// packed (rep,dim) index tables: 16 = 1+3+5+7 entries
__constant__ int P2R_c[16] = {0, 1,1,1, 2,2,2,2,2, 3,3,3,3,3,3,3};
__constant__ int P2D_c[16] = {0, 0,1,2, 0,1,2,3,4, 0,1,2,3,4,5,6};
__constant__ int DIMS_c[4] = {1,3,5,7};
__constant__ int OFF_c[4]  = {0,1,4,9};

__device__ inline float2 cmadd(float2 acc, float2 a, float2 b){
    acc.x += a.x*b.x - a.y*b.y;
    acc.y += a.x*b.y + a.y*b.x;
    return acc;
}

// One prep kernel, three flat ranges:
//  [0, 2352)            cgf[k][qr][s][t] = sum_g cg[g,3,s,3,t,q,r]*f[k,q,g]
//  [2352, 2352+16384)   PK2[ls][mt][qr][g] = cg[g,l,s,m,t,q,r]
//  [18736, 18736+49152) pack V -> Vp[x][j][mt16][c16]
#define PREP_TOTAL (2352 + 16384 + 49152)
__global__ void prep_kernel(const float* __restrict__ cg,
                            const float* __restrict__ f,
                            const float* __restrict__ Vin,
                            float* __restrict__ cgf,
                            float* __restrict__ PK2,
                            float* __restrict__ Vp){
    int idx = blockIdx.x*256 + threadIdx.x;
    if (idx < 2352){
        int k  = idx / (16*49);
        int rem = idx % (16*49);
        int qr = rem / 49;
        int st = rem % 49;
        int s = st / 7, t = st % 7;
        int q = P2R_c[qr], r = P2D_c[qr];
        float2 acc = make_float2(0.f, 0.f);
        for (int g = 0; g < 4; ++g){
            const float* cgp = cg + (((((((size_t)g*4+3)*7 + s)*4 + 3)*7 + t)*4 + q)*7 + r)*2;
            const float* fp  = f + ((k*4 + q)*4 + g)*2;
            acc = cmadd(acc, make_float2(cgp[0], cgp[1]), make_float2(fp[0], fp[1]));
        }
        cgf[idx*2]   = acc.x;
        cgf[idx*2+1] = acc.y;
    } else if (idx < 2352 + 16384){
        int id = idx - 2352;           // = ((ls*16+mt)*16+qr)*4+g
        int g  = id & 3;
        int qr = (id >> 2) & 15;
        int mt = (id >> 6) & 15;
        int ls = (id >> 10) & 15;
        int l = P2R_c[ls], s = P2D_c[ls];
        int m = P2R_c[mt], t = P2D_c[mt];
        int q = P2R_c[qr], r = P2D_c[qr];
        size_t co = (((((((size_t)g*4 + l)*7 + s)*4 + m)*7 + t)*4 + q)*7 + r);
        PK2[id*2]   = cg[co*2];
        PK2[id*2+1] = cg[co*2+1];
    } else if (idx < PREP_TOTAL){
        int id = idx - 18736;          // = (xj*16+mt)*16+c
        int c  = id & 15;
        int mt = (id >> 4) & 15;
        int xj = id >> 8;
        int m = P2R_c[mt], t = P2D_c[mt];
        const float* p = Vin + ((((size_t)xj*4 + m)*16 + c)*7 + t)*2;
        Vp[id*2]   = p[0];
        Vp[id*2+1] = p[1];
    }
}

// filt_all_kernel: grid 3*192 + 12 zero-blocks, 256 threads.
#define ZBLK 12
__global__ __launch_bounds__(256)
void filt_all_kernel(const float* __restrict__ X,
                     const float* __restrict__ cgf,     // [k][16][49] complex
                     float* __restrict__ filt_g,        // [k][xi][96][16] complex
                     float* __restrict__ zbase)         // VB (3 buffers contiguous)
{
    if (blockIdx.x >= NLAY*NXI){
        const int zb = blockIdx.x - NLAY*NXI;
        float4* dst = (float4*)zbase;
        const int base = (zb*256 + (int)threadIdx.x)*24;
        const float4 z4 = make_float4(0.f,0.f,0.f,0.f);
        #pragma unroll
        for (int u = 0; u < 24; ++u) dst[base + u] = z4;
        return;
    }

    __shared__ float2 cgf_s[784];      // 6272 B
    __shared__ float2 dX_s[NP][7];     // 5376 B

    const int tid = threadIdx.x;
    const int k  = blockIdx.x / NXI;
    const int xi = blockIdx.x % NXI;
    const int x = xi / NP, i = xi % NP;

    const float2* cgf_k = (const float2*)cgf + (size_t)k*784;
    for (int u = tid; u < 784; u += 256) cgf_s[u] = cgf_k[u];
    for (int e = tid; e < NP*7; e += 256){
        int j = e / 7, s = e % 7;
        const float* Xj = X + (((size_t)x*NP + j)*7 + s)*2;
        const float* Xi = X + (((size_t)x*NP + i)*7 + s)*2;
        dX_s[j][s] = make_float2(Xj[0]-Xi[0], Xj[1]-Xi[1]);
    }
    __syncthreads();

    float2* out = (float2*)filt_g + (size_t)blockIdx.x*NP*16;
    for (int e = tid; e < NP*16; e += 256){
        int j = e >> 4, qr = e & 15;
        const float2* cb = cgf_s + qr*49;
        float2 acc = make_float2(0.f, 0.f);
        #pragma unroll
        for (int s = 0; s < 7; ++s){
            float2 inner = make_float2(0.f, 0.f);
            #pragma unroll
            for (int t = 0; t < 7; ++t)
                inner = cmadd(inner, cb[s*7 + t], dX_s[j][t]);
            acc = cmadd(acc, dX_s[j][s], inner);
        }
        if (qr >= 9){ float2 dv = dX_s[j][qr-9]; acc.x += dv.x; acc.y += dv.y; }
        out[e] = acc;
    }
}

// TS_kernel: grid 768 = cq*192 + xi (xi fastest -> XCD-local), 512 threads.
// Round-13's exact work distribution (no duplicated FLOPs) at 2x the waves:
// 3 blocks/CU x 8 waves = 24 waves/CU (~75% occupancy).
//  T: thread = (jg2, ls16, colq16), acc[4], 48 j each, 2-stage jg reduce.
//  S: thread = (clh2, lsq4, qg64); wave owns (clh,lsq) -> 64 lm, sacc[2];
//     PK read 2x/block (reads only); 4-stage lsq reduce, disjoint clh halves.
//  W: threads 0..255, atomic accumulate (Vout pre-zeroed).
// Barriers/block: 8. LDS 22.8 KB. launch_bounds(512,6) -> VGPR cap 85.
__global__ __launch_bounds__(512, 6)
void TS_kernel(const float* __restrict__ filt_gk,  // [xi][96][16] complex
               const float* __restrict__ PK2,      // [ls][mt][qr][g] complex
               const float* __restrict__ W_k,      // [q][c][g][d] complex
               const float* __restrict__ Vin,      // packed [x][j][mtc]
               float* __restrict__ Vout)           // packed [xi][qr*16+d], pre-zeroed
{
    __shared__ __align__(16) float2 filt_s[NP][16];  // 12288 B
    __shared__ __align__(16) float2 T_s[16][66];     // 8448 B (rows padded +2)
    __shared__ __align__(16) float2 S_s[256];        // 2048 B  [cl][qg]

    const int tid = threadIdx.x;
    const int xi = blockIdx.x % NXI;   // xi fastest -> XCD-local
    const int cq = blockIdx.x / NXI;
    const int x  = xi / NP;

    // stage filters for this xi (24 KB, same-XCD L2 hit)
    {
        const float2* src = (const float2*)filt_gk + (size_t)xi*NP*16;
        float2* dst = &filt_s[0][0];
        for (int e = tid; e < NP*16; e += 512) dst[e] = src[e];
    }
    __syncthreads();

    // ---- phase T: T[ls][colq*4+cl] = sum_j filt[j][ls]*V[j][colq*16+cq*4+cl]
    const int jg   = tid >> 8;         // 0..1
    const int ls   = (tid >> 4) & 15;
    const int colq = tid & 15;         // = mt
    {
        const float4* V4 = (const float4*)((const float2*)Vin + (size_t)x*NP*256);
        float2 acc0 = make_float2(0.f,0.f), acc1 = acc0, acc2 = acc0, acc3 = acc0;
        const int j0 = jg*48;
        const int vcol = colq*8 + cq*2;    // float4 units within 128-f4 row
        #pragma unroll 4
        for (int jj = 0; jj < 48; ++jj){
            const int j = j0 + jj;
            float2 fv = filt_s[j][ls];
            float4 va = V4[j*128 + vcol];
            float4 vb = V4[j*128 + vcol + 1];
            acc0 = cmadd(acc0, fv, make_float2(va.x, va.y));
            acc1 = cmadd(acc1, fv, make_float2(va.z, va.w));
            acc2 = cmadd(acc2, fv, make_float2(vb.x, vb.y));
            acc3 = cmadd(acc3, fv, make_float2(vb.z, vb.w));
        }
        // 2-stage jg reduction into T_s
        if (jg == 0){
            float4* Trow = (float4*)&T_s[ls][0];   // 33 float4/row
            Trow[colq*2]   = make_float4(acc0.x, acc0.y, acc1.x, acc1.y);
            Trow[colq*2+1] = make_float4(acc2.x, acc2.y, acc3.x, acc3.y);
        }
        __syncthreads();
        if (jg == 1){
            float2 tp;
            tp = T_s[ls][colq*4];   tp.x += acc0.x; tp.y += acc0.y; T_s[ls][colq*4]   = tp;
            tp = T_s[ls][colq*4+1]; tp.x += acc1.x; tp.y += acc1.y; T_s[ls][colq*4+1] = tp;
            tp = T_s[ls][colq*4+2]; tp.x += acc2.x; tp.y += acc2.y; T_s[ls][colq*4+2] = tp;
            tp = T_s[ls][colq*4+3]; tp.x += acc3.x; tp.y += acc3.y; T_s[ls][colq*4+3] = tp;
        }
        __syncthreads();
    }

    // ---- phase S: S[cl][qg] = sum_{lm} PK[lm][qg] * T[lm>>4][(lm&15)*4+cl]
    // wave w = (clh, lsq): lm quarter per lsq, 2 channels per clh.
    {
        const int w    = tid >> 6;        // 0..7
        const int clh  = w >> 2;          // 0..1 -> cl = {2clh, 2clh+1}
        const int lsq2 = w & 3;           // lm quarter
        const int qg   = tid & 63;        // qr*4+g
        const float2* PKp = (const float2*)PK2 + qg;
        float2 sacc0 = make_float2(0.f, 0.f), sacc1 = sacc0;
        #pragma unroll 4
        for (int lml = 0; lml < 64; ++lml){
            const int lm = lsq2*64 + lml;
            float2 pk = PKp[(size_t)lm*64];
            const int ls2 = lm >> 4, c0 = (lm & 15)*4 + clh*2;
            sacc0 = cmadd(sacc0, pk, T_s[ls2][c0]);
            sacc1 = cmadd(sacc1, pk, T_s[ls2][c0 + 1]);
        }
        // 4-stage lsq2 reduction into S_s (clh halves disjoint)
        for (int st = 0; st < 4; ++st){
            if (lsq2 == st){
                if (st == 0){
                    S_s[(clh*2)*64 + qg]     = sacc0;
                    S_s[(clh*2 + 1)*64 + qg] = sacc1;
                } else {
                    float2 sp;
                    sp = S_s[(clh*2)*64 + qg];
                    sp.x += sacc0.x; sp.y += sacc0.y;
                    S_s[(clh*2)*64 + qg] = sp;
                    sp = S_s[(clh*2 + 1)*64 + qg];
                    sp.x += sacc1.x; sp.y += sacc1.y;
                    S_s[(clh*2 + 1)*64 + qg] = sp;
                }
            }
            __syncthreads();
        }
    }

    // ---- phase W (partial over this cq): Vout[qr][d] += sum_{cl,g} S*W
    if (tid < 256){
        const int qr2 = tid >> 4, d = tid & 15;
        const int q = P2R_c[qr2];
        float2 acc = make_float2(0.f, 0.f);
        const float2* Wb = (const float2*)W_k + (size_t)q*16*4*16 + d;
        #pragma unroll
        for (int cl2 = 0; cl2 < 4; ++cl2){
            const int c = cq*4 + cl2;
            #pragma unroll
            for (int g2 = 0; g2 < 4; ++g2){
                float2 sv = S_s[cl2*64 + qr2*4 + g2];
                float2 wv = Wb[(c*4 + g2)*16];
                acc = cmadd(acc, sv, wv);
            }
        }
        float* outp = (float*)Vout + ((size_t)xi*256 + tid)*2;
        atomicAdd(outp,     acc.x);
        atomicAdd(outp + 1, acc.y);
    }
}

// unpack final packed V -> d_out (x,i,q,d,r,z), zeros at r >= DIMS[q]
__global__ void unpack_V_kernel(const float* __restrict__ Vp,
                                float* __restrict__ out){
    int idx = blockIdx.x*blockDim.x + threadIdx.x;
    if (idx >= XS*NP*4*16*7) return;
    int r  = idx % 7;
    int d  = (idx / 7) % 16;
    int q  = (idx / (7*16)) % 4;
    int xi = idx / (7*16*4);
    float2 v = make_float2(0.f, 0.f);
    if (r < DIMS_c[q]){
        v = ((const float2*)Vp)[(size_t)xi*256 + (OFF_c[q] + r)*16 + d];
    }
    ((float2*)out)[idx] = v;
}

extern "C" void kernel_launch(void* const* d_in, const int* in_sizes, int n_in,
                              void* d_out, int out_size, void* d_ws, size_t ws_size,
                              hipStream_t stream) {
    const float* X  = (const float*)d_in[0];
    // d_in[1] is 'l' (always 3, hardcoded)
    const float* V  = (const float*)d_in[2];
    const float* cg = (const float*)d_in[3];
    const float* f  = (const float*)d_in[4];
    const float* W  = (const float*)d_in[5];
    // d_in[6] is C4 (plain complex product, hardcoded)

    // ws layout (floats)
    float* ws     = (float*)d_ws;
    float* cgf    = ws;                         // 3*784*2   = 4704
    float* PK2    = cgf   + 4704;               // 16384*2   = 32768
    float* VA     = PK2   + 32768;              // 192*256*2 = 98304
    float* VB     = VA + 98304;                 // 98304
    float* VC     = VB + 98304;                 // 98304
    float* VD     = VC + 98304;                 // 98304
    float* filt_g = VD + 98304;                 // 3*192*96*16*2 = 1769472

    prep_kernel<<<(PREP_TOTAL + 255)/256, 256, 0, stream>>>(cg, f, V, cgf, PK2, VA);
    // filters for all layers + zero VB/VC/VD (contiguous)
    filt_all_kernel<<<NLAY*NXI + ZBLK, 256, 0, stream>>>(X, cgf, filt_g, VB);

    const float* W0 = W;
    const float* W1 = W + (size_t)1*4*16*4*16*2;
    const float* W2 = W + (size_t)2*4*16*4*16*2;
    const float* f0 = filt_g;
    const float* f1 = filt_g + (size_t)1*NXI*NP*16*2;
    const float* f2 = filt_g + (size_t)2*NXI*NP*16*2;

    TS_kernel<<<NXI*4, 512, 0, stream>>>(f0, PK2, W0, VA, VB);
    TS_kernel<<<NXI*4, 512, 0, stream>>>(f1, PK2, W1, VB, VC);
    TS_kernel<<<NXI*4, 512, 0, stream>>>(f2, PK2, W2, VC, VD);

    unpack_V_kernel<<<(XS*NP*4*16*7 + 255)/256, 256, 0, stream>>>(VD, (float*)d_out);
}

// Round 16
// 101.629 us; speedup vs baseline: 2.6443x; 2.6443x over previous
//
#include <hip/hip_runtime.h>
#include <hip/hip_bf16.h>

// Problem constants (shapes fixed by the reference)
#define XS   2
#define NP   96
#define NLAY 3
#define NXI  (XS*NP)   // 192
#define VBF_ARR (XS*256*96)   // 49152 ushorts per component array

// packed (rep,dim) index tables: 16 = 1+3+5+7 entries
__constant__ int P2R_c[16] = {0, 1,1,1, 2,2,2,2,2, 3,3,3,3,3,3,3};
__constant__ int P2D_c[16] = {0, 0,1,2, 0,1,2,3,4, 0,1,2,3,4,5,6};
__constant__ int DIMS_c[4] = {1,3,5,7};
__constant__ int OFF_c[4]  = {0,1,4,9};

typedef __attribute__((ext_vector_type(8))) short bf16x8;
typedef __attribute__((ext_vector_type(4))) float f32x4;

__device__ inline float2 cmadd(float2 acc, float2 a, float2 b){
    acc.x += a.x*b.x - a.y*b.y;
    acc.y += a.x*b.y + a.y*b.x;
    return acc;
}
__device__ inline unsigned short f2bf(float v){
    __hip_bfloat16 h = __float2bfloat16(v);
    union { __hip_bfloat16 h; unsigned short u; } cv; cv.h = h; return cv.u;
}
__device__ inline float bf2f(unsigned short u){
    union { unsigned short u; __hip_bfloat16 h; } cv; cv.u = u;
    return __bfloat162float(cv.h);
}

// prep: three flat ranges
//  [0,2352)        cgf[k][qr][s][t] = sum_g cg[g,3,s,3,t,q,r]*f[k,q,g]
//  [2352,18736)    PK2[ls][mt][qr][g] = cg[g,l,s,m,t,q,r]
//  [18736,67888)   Vbf0: packed V -> bf16 hi/lo col-major [arr][x][n=mtc][k=j]
#define PREP_TOTAL (2352 + 16384 + XS*256*96)
__global__ void prep_kernel(const float* __restrict__ cg,
                            const float* __restrict__ f,
                            const float* __restrict__ Vin,
                            float* __restrict__ cgf,
                            float* __restrict__ PK2,
                            unsigned short* __restrict__ Vbf0){
    int idx = blockIdx.x*256 + threadIdx.x;
    if (idx < 2352){
        int k  = idx / (16*49);
        int rem = idx % (16*49);
        int qr = rem / 49;
        int st = rem % 49;
        int s = st / 7, t = st % 7;
        int q = P2R_c[qr], r = P2D_c[qr];
        float2 acc = make_float2(0.f, 0.f);
        for (int g = 0; g < 4; ++g){
            const float* cgp = cg + (((((((size_t)g*4+3)*7 + s)*4 + 3)*7 + t)*4 + q)*7 + r)*2;
            const float* fp  = f + ((k*4 + q)*4 + g)*2;
            acc = cmadd(acc, make_float2(cgp[0], cgp[1]), make_float2(fp[0], fp[1]));
        }
        cgf[idx*2]   = acc.x;
        cgf[idx*2+1] = acc.y;
    } else if (idx < 18736){
        int id = idx - 2352;           // = ((ls*16+mt)*16+qr)*4+g
        int g  = id & 3;
        int qr = (id >> 2) & 15;
        int mt = (id >> 6) & 15;
        int ls = (id >> 10) & 15;
        int l = P2R_c[ls], s = P2D_c[ls];
        int m = P2R_c[mt], t = P2D_c[mt];
        int q = P2R_c[qr], r = P2D_c[qr];
        size_t co = (((((((size_t)g*4 + l)*7 + s)*4 + m)*7 + t)*4 + q)*7 + r);
        PK2[id*2]   = cg[co*2];
        PK2[id*2+1] = cg[co*2+1];
    } else if (idx < PREP_TOTAL){
        int id = idx - 18736;          // = (x*256+n)*96 + kj
        int kj = id % 96;
        int n  = (id / 96) % 256;
        int x  = id / (96*256);
        int mt = n >> 4, c = n & 15;
        int m = P2R_c[mt], t = P2D_c[mt];
        const float* p = Vin + ((((size_t)(x*NP + kj)*4 + m)*16 + c)*7 + t)*2;
        float re = p[0], im = p[1];
        unsigned short h;
        h = f2bf(re); Vbf0[0*VBF_ARR + id] = h;
        Vbf0[1*VBF_ARR + id] = f2bf(re - bf2f(h));
        h = f2bf(im); Vbf0[2*VBF_ARR + id] = h;
        Vbf0[3*VBF_ARR + id] = f2bf(im - bf2f(h));
    }
}

// filt_all_kernel: grid 3*192, 256 threads. Filters for all 3 layers.
__global__ __launch_bounds__(256)
void filt_all_kernel(const float* __restrict__ X,
                     const float* __restrict__ cgf,     // [k][16][49] complex
                     float* __restrict__ filt_g)        // [k][xi][96][16] complex
{
    __shared__ float2 cgf_s[784];
    __shared__ float2 dX_s[NP][7];

    const int tid = threadIdx.x;
    const int k  = blockIdx.x / NXI;
    const int xi = blockIdx.x % NXI;
    const int x = xi / NP, i = xi % NP;

    const float2* cgf_k = (const float2*)cgf + (size_t)k*784;
    for (int u = tid; u < 784; u += 256) cgf_s[u] = cgf_k[u];
    for (int e = tid; e < NP*7; e += 256){
        int j = e / 7, s = e % 7;
        const float* Xj = X + (((size_t)x*NP + j)*7 + s)*2;
        const float* Xi = X + (((size_t)x*NP + i)*7 + s)*2;
        dX_s[j][s] = make_float2(Xj[0]-Xi[0], Xj[1]-Xi[1]);
    }
    __syncthreads();

    float2* out = (float2*)filt_g + (size_t)blockIdx.x*NP*16;
    for (int e = tid; e < NP*16; e += 256){
        int j = e >> 4, qr = e & 15;
        const float2* cb = cgf_s + qr*49;
        float2 acc = make_float2(0.f, 0.f);
        #pragma unroll
        for (int s = 0; s < 7; ++s){
            float2 inner = make_float2(0.f, 0.f);
            #pragma unroll
            for (int t = 0; t < 7; ++t)
                inner = cmadd(inner, cb[s*7 + t], dX_s[j][t]);
            acc = cmadd(acc, dX_s[j][s], inner);
        }
        if (qr >= 9){ float2 dv = dX_s[j][qr-9]; acc.x += dv.x; acc.y += dv.y; }
        out[e] = acc;
    }
}

// TS_kernel: one block per xi, 512 threads (8 waves).
// T phase on MFMA (bf16 hi/lo split, 4 real matmuls M16 K96 N256),
// S phase VALU, W phase writes fp32 Vout + next layer's bf16 hi/lo operand.
// No atomics (block owns all channels of its xi).
__global__ __launch_bounds__(512, 2)
void TS_kernel(const float* __restrict__ filt_gk,      // [xi][96][16] complex
               const float* __restrict__ PK2,          // [ls][mt][qr][g] complex
               const float* __restrict__ W_k,          // [q][c][g][d] complex
               const unsigned short* __restrict__ Vbf_in,  // [4][x][n][k] bf16
               unsigned short* __restrict__ Vbf_out,       // same, next layer
               float* __restrict__ Vout)               // packed [xi][qr*16+d] fp32
{
    // A-operand buffers: F^T row-major [16 ls][104 k] bf16 (pad k for banks)
    __shared__ unsigned short Abuf[6][16][104];   // FrH,FrL,FiH,FiL,nFiH,nFiL: 19968 B
    __shared__ __align__(16) float2 T_s[16][258]; // 33024 B
    __shared__ float2 S_s[16*64];                 // 8192 B   (total ~59.8 KB)

    const int tid = threadIdx.x;
    const int xi = blockIdx.x;
    const int x = xi / NP, i = xi % NP;

    // build bf16 hi/lo A-operands from fp32 filters (L2-hot, 12 KB)
    for (int e = tid; e < NP*16; e += 512){
        const int j = e >> 4, ls = e & 15;
        float2 fv = ((const float2*)filt_gk)[((size_t)xi*NP + j)*16 + ls];
        unsigned short h = f2bf(fv.x);
        Abuf[0][ls][j] = h;
        Abuf[1][ls][j] = f2bf(fv.x - bf2f(h));
        h = f2bf(fv.y);
        unsigned short lo = f2bf(fv.y - bf2f(h));
        Abuf[2][ls][j] = h;
        Abuf[3][ls][j] = lo;
        Abuf[4][ls][j] = h  ^ 0x8000;   // -Fi (exact)
        Abuf[5][ls][j] = lo ^ 0x8000;
    }
    __syncthreads();

    // ---- phase T (MFMA): T[ls][n] = sum_j F[j][ls]*V[j][n] (complex)
    // Tr = Fr*Vr + (-Fi)*Vi ; Ti = Fr*Vi + Fi*Vr, each product = 3 bf16 MFMAs
    // (hi*hi + hi*lo + lo*hi). Wave w owns n in [w*32, w*32+32).
    const int w    = tid >> 6;
    const int lane = tid & 63;
    const int lrow = lane & 15;          // A row / B col / D col
    const int kb   = (lane >> 4) * 8;    // k sub-offset within K=32 step
    {
        f32x4 accR[2], accI[2];
        #pragma unroll
        for (int nt = 0; nt < 2; ++nt){
            accR[nt] = (f32x4){0.f,0.f,0.f,0.f};
            accI[nt] = (f32x4){0.f,0.f,0.f,0.f};
        }
        const unsigned short* Vrh = Vbf_in + 0*VBF_ARR + (size_t)x*256*96;
        const unsigned short* Vrl = Vbf_in + 1*VBF_ARR + (size_t)x*256*96;
        const unsigned short* Vih = Vbf_in + 2*VBF_ARR + (size_t)x*256*96;
        const unsigned short* Vil = Vbf_in + 3*VBF_ARR + (size_t)x*256*96;
        #pragma unroll
        for (int kt = 0; kt < 3; ++kt){
            const int ka = kt*32 + kb;
            bf16x8 frh = *(const bf16x8*)&Abuf[0][lrow][ka];
            bf16x8 frl = *(const bf16x8*)&Abuf[1][lrow][ka];
            bf16x8 fih = *(const bf16x8*)&Abuf[2][lrow][ka];
            bf16x8 fil = *(const bf16x8*)&Abuf[3][lrow][ka];
            bf16x8 nfh = *(const bf16x8*)&Abuf[4][lrow][ka];
            bf16x8 nfl = *(const bf16x8*)&Abuf[5][lrow][ka];
            #pragma unroll
            for (int nt = 0; nt < 2; ++nt){
                const int n = w*32 + nt*16 + lrow;
                const size_t bo = (size_t)n*96 + ka;
                bf16x8 vrh = *(const bf16x8*)(Vrh + bo);
                bf16x8 vrl = *(const bf16x8*)(Vrl + bo);
                bf16x8 vih = *(const bf16x8*)(Vih + bo);
                bf16x8 vil = *(const bf16x8*)(Vil + bo);
                // Tr += Fr*Vr - Fi*Vi
                accR[nt] = __builtin_amdgcn_mfma_f32_16x16x32_bf16(frh, vrh, accR[nt], 0,0,0);
                accR[nt] = __builtin_amdgcn_mfma_f32_16x16x32_bf16(frh, vrl, accR[nt], 0,0,0);
                accR[nt] = __builtin_amdgcn_mfma_f32_16x16x32_bf16(frl, vrh, accR[nt], 0,0,0);
                accR[nt] = __builtin_amdgcn_mfma_f32_16x16x32_bf16(nfh, vih, accR[nt], 0,0,0);
                accR[nt] = __builtin_amdgcn_mfma_f32_16x16x32_bf16(nfh, vil, accR[nt], 0,0,0);
                accR[nt] = __builtin_amdgcn_mfma_f32_16x16x32_bf16(nfl, vih, accR[nt], 0,0,0);
                // Ti += Fr*Vi + Fi*Vr
                accI[nt] = __builtin_amdgcn_mfma_f32_16x16x32_bf16(frh, vih, accI[nt], 0,0,0);
                accI[nt] = __builtin_amdgcn_mfma_f32_16x16x32_bf16(frh, vil, accI[nt], 0,0,0);
                accI[nt] = __builtin_amdgcn_mfma_f32_16x16x32_bf16(frl, vih, accI[nt], 0,0,0);
                accI[nt] = __builtin_amdgcn_mfma_f32_16x16x32_bf16(fih, vrh, accI[nt], 0,0,0);
                accI[nt] = __builtin_amdgcn_mfma_f32_16x16x32_bf16(fih, vrl, accI[nt], 0,0,0);
                accI[nt] = __builtin_amdgcn_mfma_f32_16x16x32_bf16(fil, vrh, accI[nt], 0,0,0);
            }
        }
        // D layout: row = (lane>>4)*4 + r, col = lane&15 (verified m89)
        #pragma unroll
        for (int nt = 0; nt < 2; ++nt){
            #pragma unroll
            for (int r = 0; r < 4; ++r){
                T_s[(lane>>4)*4 + r][w*32 + nt*16 + lrow] =
                    make_float2(accR[nt][r], accI[nt][r]);
            }
        }
    }
    __syncthreads();

    // ---- phase S: S[cl][qg] = sum_lm PK[lm][qg] * T[lm>>4][(lm&15)*16+cl]
    // thread = (clp 0..7, qg 0..63), owns cl = {clp, clp+8}; PK loads are
    // 512B wave-coalesced, identical across waves (L1/L2-served).
    {
        const int clp = tid >> 6;
        const int qg  = tid & 63;
        const float2* PKp = (const float2*)PK2 + qg;
        float2 s0 = make_float2(0.f,0.f), s1 = make_float2(0.f,0.f);
        #pragma unroll 8
        for (int lm = 0; lm < 256; ++lm){
            float2 pk = PKp[(size_t)lm*64];
            const int ls2 = lm >> 4, mtb = (lm & 15)*16;
            s0 = cmadd(s0, pk, T_s[ls2][mtb + clp]);
            s1 = cmadd(s1, pk, T_s[ls2][mtb + clp + 8]);
        }
        S_s[clp*64 + qg]     = s0;
        S_s[(clp+8)*64 + qg] = s1;
    }
    __syncthreads();

    // ---- phase W: Vout[qr][d] = sum_{c,g} S[c][qr*4+g]*W[q][c][g][d]
    // + emit next layer's bf16 hi/lo operand at [arr][x][n=tid][k=i].
    if (tid < 256){
        const int qr2 = tid >> 4, d = tid & 15;
        const int q = P2R_c[qr2];
        float2 acc = make_float2(0.f, 0.f);
        const float2* Wb = (const float2*)W_k + (size_t)q*16*4*16 + d;
        #pragma unroll 4
        for (int c = 0; c < 16; ++c){
            #pragma unroll
            for (int g = 0; g < 4; ++g){
                acc = cmadd(acc, S_s[c*64 + qr2*4 + g], Wb[(c*4 + g)*16]);
            }
        }
        ((float2*)Vout)[(size_t)xi*256 + tid] = acc;
        const size_t vo = ((size_t)x*256 + tid)*96 + i;
        unsigned short h;
        h = f2bf(acc.x); Vbf_out[0*VBF_ARR + vo] = h;
        Vbf_out[1*VBF_ARR + vo] = f2bf(acc.x - bf2f(h));
        h = f2bf(acc.y); Vbf_out[2*VBF_ARR + vo] = h;
        Vbf_out[3*VBF_ARR + vo] = f2bf(acc.y - bf2f(h));
    }
}

// unpack final packed V -> d_out (x,i,q,d,r,z), zeros at r >= DIMS[q]
__global__ void unpack_V_kernel(const float* __restrict__ Vp,
                                float* __restrict__ out){
    int idx = blockIdx.x*blockDim.x + threadIdx.x;
    if (idx >= XS*NP*4*16*7) return;
    int r  = idx % 7;
    int d  = (idx / 7) % 16;
    int q  = (idx / (7*16)) % 4;
    int xi = idx / (7*16*4);
    float2 v = make_float2(0.f, 0.f);
    if (r < DIMS_c[q]){
        v = ((const float2*)Vp)[(size_t)xi*256 + (OFF_c[q] + r)*16 + d];
    }
    ((float2*)out)[idx] = v;
}

extern "C" void kernel_launch(void* const* d_in, const int* in_sizes, int n_in,
                              void* d_out, int out_size, void* d_ws, size_t ws_size,
                              hipStream_t stream) {
    const float* X  = (const float*)d_in[0];
    // d_in[1] is 'l' (always 3, hardcoded)
    const float* V  = (const float*)d_in[2];
    const float* cg = (const float*)d_in[3];
    const float* f  = (const float*)d_in[4];
    const float* W  = (const float*)d_in[5];
    // d_in[6] is C4 (plain complex product, hardcoded)

    // ws layout (floats): cgf 4704 | PK2 32768 | Vout 98304 |
    // VbfA 98304 | VbfB 98304 | filt_g 1769472   (~8.4 MB total)
    float* ws    = (float*)d_ws;
    float* cgf   = ws;
    float* PK2   = ws + 4704;
    float* Vout  = ws + 4704 + 32768;
    unsigned short* VbfA = (unsigned short*)(ws + 135776);
    unsigned short* VbfB = (unsigned short*)(ws + 135776 + 98304);
    float* filt_g = ws + 135776 + 196608;

    prep_kernel<<<(PREP_TOTAL + 255)/256, 256, 0, stream>>>(cg, f, V, cgf, PK2, VbfA);
    filt_all_kernel<<<NLAY*NXI, 256, 0, stream>>>(X, cgf, filt_g);

    const float* W0 = W;
    const float* W1 = W + (size_t)1*4*16*4*16*2;
    const float* W2 = W + (size_t)2*4*16*4*16*2;
    const float* f0 = filt_g;
    const float* f1 = filt_g + (size_t)1*NXI*NP*16*2;
    const float* f2 = filt_g + (size_t)2*NXI*NP*16*2;

    TS_kernel<<<NXI, 512, 0, stream>>>(f0, PK2, W0, VbfA, VbfB, Vout);
    TS_kernel<<<NXI, 512, 0, stream>>>(f1, PK2, W1, VbfB, VbfA, Vout);
    TS_kernel<<<NXI, 512, 0, stream>>>(f2, PK2, W2, VbfA, VbfB, Vout);

    unpack_V_kernel<<<(XS*NP*4*16*7 + 255)/256, 256, 0, stream>>>(Vout, (float*)d_out);
}

// Round 17
// 74.234 us; speedup vs baseline: 3.6201x; 1.3690x over previous
//
#include <hip/hip_runtime.h>
#include <hip/hip_bf16.h>

// Problem constants (shapes fixed by the reference)
#define XS   2
#define NP   96
#define NLAY 3
#define NXI  (XS*NP)   // 192
#define VBF_ARR (XS*256*96)   // 49152 ushorts per component array

// packed (rep,dim) index tables: 16 = 1+3+5+7 entries
__constant__ int P2R_c[16] = {0, 1,1,1, 2,2,2,2,2, 3,3,3,3,3,3,3};
__constant__ int P2D_c[16] = {0, 0,1,2, 0,1,2,3,4, 0,1,2,3,4,5,6};
__constant__ int DIMS_c[4] = {1,3,5,7};
__constant__ int OFF_c[4]  = {0,1,4,9};

typedef __attribute__((ext_vector_type(8))) short bf16x8;
typedef __attribute__((ext_vector_type(4))) float f32x4;

__device__ inline float2 cmadd(float2 acc, float2 a, float2 b){
    acc.x += a.x*b.x - a.y*b.y;
    acc.y += a.x*b.y + a.y*b.x;
    return acc;
}
__device__ inline unsigned short f2bf(float v){
    __hip_bfloat16 h = __float2bfloat16(v);
    union { __hip_bfloat16 h; unsigned short u; } cv; cv.h = h; return cv.u;
}
__device__ inline float bf2f(unsigned short u){
    union { unsigned short u; __hip_bfloat16 h; } cv; cv.u = u;
    return __bfloat162float(cv.h);
}

// prep: three flat ranges
//  [0,2352)        cgf[k][qr][s][t] = sum_g cg[g,3,s,3,t,q,r]*f[k,q,g]
//  [2352,18736)    PKbf[6 arr][qg=qr*4+g][lm=ls*16+mt] bf16 hi/lo (S A-operand)
//  [18736,67888)   Vbf0: packed V -> bf16 hi/lo [arr][x][n=mtc][k=j]
#define PREP_TOTAL (2352 + 16384 + XS*256*96)
__global__ void prep_kernel(const float* __restrict__ cg,
                            const float* __restrict__ f,
                            const float* __restrict__ Vin,
                            float* __restrict__ cgf,
                            unsigned short* __restrict__ PKbf,
                            unsigned short* __restrict__ Vbf0){
    int idx = blockIdx.x*256 + threadIdx.x;
    if (idx < 2352){
        int k  = idx / (16*49);
        int rem = idx % (16*49);
        int qr = rem / 49;
        int st = rem % 49;
        int s = st / 7, t = st % 7;
        int q = P2R_c[qr], r = P2D_c[qr];
        float2 acc = make_float2(0.f, 0.f);
        for (int g = 0; g < 4; ++g){
            const float* cgp = cg + (((((((size_t)g*4+3)*7 + s)*4 + 3)*7 + t)*4 + q)*7 + r)*2;
            const float* fp  = f + ((k*4 + q)*4 + g)*2;
            acc = cmadd(acc, make_float2(cgp[0], cgp[1]), make_float2(fp[0], fp[1]));
        }
        cgf[idx*2]   = acc.x;
        cgf[idx*2+1] = acc.y;
    } else if (idx < 18736){
        int id = idx - 2352;           // = qg*256 + lm
        int lm = id & 255;
        int qg = id >> 8;
        int ls = lm >> 4, mt = lm & 15;
        int qr = qg >> 2, g = qg & 3;
        int l = P2R_c[ls], s = P2D_c[ls];
        int m = P2R_c[mt], t = P2D_c[mt];
        int q = P2R_c[qr], r = P2D_c[qr];
        size_t co = (((((((size_t)g*4 + l)*7 + s)*4 + m)*7 + t)*4 + q)*7 + r);
        float re = cg[co*2], im = cg[co*2+1];
        unsigned short rh = f2bf(re), rl = f2bf(re - bf2f(rh));
        unsigned short ih = f2bf(im), il = f2bf(im - bf2f(ih));
        PKbf[0*16384 + id] = rh;
        PKbf[1*16384 + id] = rl;
        PKbf[2*16384 + id] = ih;
        PKbf[3*16384 + id] = il;
        PKbf[4*16384 + id] = ih ^ 0x8000;
        PKbf[5*16384 + id] = il ^ 0x8000;
    } else if (idx < PREP_TOTAL){
        int id = idx - 18736;          // = (x*256+n)*96 + kj
        int kj = id % 96;
        int n  = (id / 96) % 256;
        int x  = id / (96*256);
        int mt = n >> 4, c = n & 15;
        int m = P2R_c[mt], t = P2D_c[mt];
        const float* p = Vin + ((((size_t)(x*NP + kj)*4 + m)*16 + c)*7 + t)*2;
        float re = p[0], im = p[1];
        unsigned short h;
        h = f2bf(re); Vbf0[0*VBF_ARR + id] = h;
        Vbf0[1*VBF_ARR + id] = f2bf(re - bf2f(h));
        h = f2bf(im); Vbf0[2*VBF_ARR + id] = h;
        Vbf0[3*VBF_ARR + id] = f2bf(im - bf2f(h));
    }
}

// filt_all_kernel: grid 3*192, 256 threads. Filters for all 3 layers.
__global__ __launch_bounds__(256)
void filt_all_kernel(const float* __restrict__ X,
                     const float* __restrict__ cgf,     // [k][16][49] complex
                     float* __restrict__ filt_g)        // [k][xi][96][16] complex
{
    __shared__ float2 cgf_s[784];
    __shared__ float2 dX_s[NP][7];

    const int tid = threadIdx.x;
    const int k  = blockIdx.x / NXI;
    const int xi = blockIdx.x % NXI;
    const int x = xi / NP, i = xi % NP;

    const float2* cgf_k = (const float2*)cgf + (size_t)k*784;
    for (int u = tid; u < 784; u += 256) cgf_s[u] = cgf_k[u];
    for (int e = tid; e < NP*7; e += 256){
        int j = e / 7, s = e % 7;
        const float* Xj = X + (((size_t)x*NP + j)*7 + s)*2;
        const float* Xi = X + (((size_t)x*NP + i)*7 + s)*2;
        dX_s[j][s] = make_float2(Xj[0]-Xi[0], Xj[1]-Xi[1]);
    }
    __syncthreads();

    float2* out = (float2*)filt_g + (size_t)blockIdx.x*NP*16;
    for (int e = tid; e < NP*16; e += 256){
        int j = e >> 4, qr = e & 15;
        const float2* cb = cgf_s + qr*49;
        float2 acc = make_float2(0.f, 0.f);
        #pragma unroll
        for (int s = 0; s < 7; ++s){
            float2 inner = make_float2(0.f, 0.f);
            #pragma unroll
            for (int t = 0; t < 7; ++t)
                inner = cmadd(inner, cb[s*7 + t], dX_s[j][t]);
            acc = cmadd(acc, dX_s[j][s], inner);
        }
        if (qr >= 9){ float2 dv = dX_s[j][qr-9]; acc.x += dv.x; acc.y += dv.y; }
        out[e] = acc;
    }
}

// TS_kernel: one block per xi, 512 threads (8 waves). Both T and S on MFMA.
//  T: M16(ls) x K96(j) x N256(mtc) complex; A=filt (LDS), B=Vbf (global).
//     Accumulators convert straight to bf16 hi/lo B-operand T2buf (LDS).
//  S: M64(qg) x K256(lm) x N16(c) complex; A=PKbf (global, prepped once),
//     B=T2buf; wave = (K-half, qtile); staged K-half reduce in S_s.
//  W: VALU channel mix -> fp32 Vout + next layer's Vbf operand.
__global__ __launch_bounds__(512, 2)
void TS_kernel(const float* __restrict__ filt_gk,      // [xi][96][16] complex
               const unsigned short* __restrict__ PKbf,// [6][64][256] bf16
               const float* __restrict__ W_k,          // [q][c][g][d] complex
               const unsigned short* __restrict__ Vbf_in,  // [4][x][n][k] bf16
               unsigned short* __restrict__ Vbf_out,       // same, next layer
               float* __restrict__ Vout)               // packed [xi][qr*16+d] fp32
{
    __shared__ __align__(16) unsigned short Abuf[6][16][104];  // 19968 B (aliased by S_s)
    __shared__ __align__(16) unsigned short T2buf[4][16][264]; // 33792 B
    float2* S_s = (float2*)&Abuf[0][0][0];                     // [qg][c] = 8192 B

    const int tid = threadIdx.x;
    const int xi = blockIdx.x;
    const int x = xi / NP, i = xi % NP;

    // build bf16 hi/lo A-operands from fp32 filters (L2-hot, 12 KB)
    for (int e = tid; e < NP*16; e += 512){
        const int j = e >> 4, ls = e & 15;
        float2 fv = ((const float2*)filt_gk)[((size_t)xi*NP + j)*16 + ls];
        unsigned short h = f2bf(fv.x);
        Abuf[0][ls][j] = h;
        Abuf[1][ls][j] = f2bf(fv.x - bf2f(h));
        h = f2bf(fv.y);
        unsigned short lo = f2bf(fv.y - bf2f(h));
        Abuf[2][ls][j] = h;
        Abuf[3][ls][j] = lo;
        Abuf[4][ls][j] = h  ^ 0x8000;   // -Fi (exact)
        Abuf[5][ls][j] = lo ^ 0x8000;
    }
    __syncthreads();

    const int w    = tid >> 6;
    const int lane = tid & 63;
    const int lrow = lane & 15;          // A row / B col / D col
    const int kb   = (lane >> 4) * 8;    // k sub-offset within K=32 step

    // ---- phase T (MFMA): T[ls][n] = sum_j F[j][ls]*V[j][n] (complex)
    {
        f32x4 accR[2], accI[2];
        #pragma unroll
        for (int nt = 0; nt < 2; ++nt){
            accR[nt] = (f32x4){0.f,0.f,0.f,0.f};
            accI[nt] = (f32x4){0.f,0.f,0.f,0.f};
        }
        const unsigned short* Vrh = Vbf_in + 0*VBF_ARR + (size_t)x*256*96;
        const unsigned short* Vrl = Vbf_in + 1*VBF_ARR + (size_t)x*256*96;
        const unsigned short* Vih = Vbf_in + 2*VBF_ARR + (size_t)x*256*96;
        const unsigned short* Vil = Vbf_in + 3*VBF_ARR + (size_t)x*256*96;
        #pragma unroll
        for (int kt = 0; kt < 3; ++kt){
            const int ka = kt*32 + kb;
            bf16x8 frh = *(const bf16x8*)&Abuf[0][lrow][ka];
            bf16x8 frl = *(const bf16x8*)&Abuf[1][lrow][ka];
            bf16x8 fih = *(const bf16x8*)&Abuf[2][lrow][ka];
            bf16x8 fil = *(const bf16x8*)&Abuf[3][lrow][ka];
            bf16x8 nfh = *(const bf16x8*)&Abuf[4][lrow][ka];
            bf16x8 nfl = *(const bf16x8*)&Abuf[5][lrow][ka];
            #pragma unroll
            for (int nt = 0; nt < 2; ++nt){
                const int n = w*32 + nt*16 + lrow;
                const size_t bo = (size_t)n*96 + ka;
                bf16x8 vrh = *(const bf16x8*)(Vrh + bo);
                bf16x8 vrl = *(const bf16x8*)(Vrl + bo);
                bf16x8 vih = *(const bf16x8*)(Vih + bo);
                bf16x8 vil = *(const bf16x8*)(Vil + bo);
                accR[nt] = __builtin_amdgcn_mfma_f32_16x16x32_bf16(frh, vrh, accR[nt], 0,0,0);
                accR[nt] = __builtin_amdgcn_mfma_f32_16x16x32_bf16(frh, vrl, accR[nt], 0,0,0);
                accR[nt] = __builtin_amdgcn_mfma_f32_16x16x32_bf16(frl, vrh, accR[nt], 0,0,0);
                accR[nt] = __builtin_amdgcn_mfma_f32_16x16x32_bf16(nfh, vih, accR[nt], 0,0,0);
                accR[nt] = __builtin_amdgcn_mfma_f32_16x16x32_bf16(nfh, vil, accR[nt], 0,0,0);
                accR[nt] = __builtin_amdgcn_mfma_f32_16x16x32_bf16(nfl, vih, accR[nt], 0,0,0);
                accI[nt] = __builtin_amdgcn_mfma_f32_16x16x32_bf16(frh, vih, accI[nt], 0,0,0);
                accI[nt] = __builtin_amdgcn_mfma_f32_16x16x32_bf16(frh, vil, accI[nt], 0,0,0);
                accI[nt] = __builtin_amdgcn_mfma_f32_16x16x32_bf16(frl, vih, accI[nt], 0,0,0);
                accI[nt] = __builtin_amdgcn_mfma_f32_16x16x32_bf16(fih, vrh, accI[nt], 0,0,0);
                accI[nt] = __builtin_amdgcn_mfma_f32_16x16x32_bf16(fih, vrl, accI[nt], 0,0,0);
                accI[nt] = __builtin_amdgcn_mfma_f32_16x16x32_bf16(fil, vrh, accI[nt], 0,0,0);
            }
        }
        // store straight to bf16 hi/lo B-operand: c = lrow, lm = ls*16 + mt,
        // ls = (lane>>4)*4 + r, mt = w*2 + nt   (D: col=lane&15, row=(lane>>4)*4+r)
        #pragma unroll
        for (int nt = 0; nt < 2; ++nt){
            #pragma unroll
            for (int r = 0; r < 4; ++r){
                const int lmp = ((lane>>4)*4 + r)*16 + (w*2 + nt);
                float tr = accR[nt][r], ti = accI[nt][r];
                unsigned short h = f2bf(tr);
                T2buf[0][lrow][lmp] = h;
                T2buf[1][lrow][lmp] = f2bf(tr - bf2f(h));
                h = f2bf(ti);
                T2buf[2][lrow][lmp] = h;
                T2buf[3][lrow][lmp] = f2bf(ti - bf2f(h));
            }
        }
    }
    __syncthreads();

    // ---- phase S (MFMA): S[qg][c] = sum_lm PK^T[qg][lm] * T2[lm][c] (complex)
    // wave w: qtile = w&3 (qg rows qtile*16..+16), K-half = w>>2 (lm 128 each).
    {
        const int qtile = w & 3;
        const int kh    = w >> 2;
        f32x4 sR = (f32x4){0.f,0.f,0.f,0.f};
        f32x4 sI = (f32x4){0.f,0.f,0.f,0.f};
        #pragma unroll
        for (int kt4 = 0; kt4 < 4; ++kt4){
            const int kt = kh*4 + kt4;
            const int ka = kt*32 + kb;
            const size_t arow = (size_t)(qtile*16 + lrow)*256 + ka;
            bf16x8 prh = *(const bf16x8*)(PKbf + 0*16384 + arow);
            bf16x8 prl = *(const bf16x8*)(PKbf + 1*16384 + arow);
            bf16x8 pih = *(const bf16x8*)(PKbf + 2*16384 + arow);
            bf16x8 pil = *(const bf16x8*)(PKbf + 3*16384 + arow);
            bf16x8 pnh = *(const bf16x8*)(PKbf + 4*16384 + arow);
            bf16x8 pnl = *(const bf16x8*)(PKbf + 5*16384 + arow);
            bf16x8 trh = *(const bf16x8*)&T2buf[0][lrow][ka];
            bf16x8 trl = *(const bf16x8*)&T2buf[1][lrow][ka];
            bf16x8 tih = *(const bf16x8*)&T2buf[2][lrow][ka];
            bf16x8 til = *(const bf16x8*)&T2buf[3][lrow][ka];
            sR = __builtin_amdgcn_mfma_f32_16x16x32_bf16(prh, trh, sR, 0,0,0);
            sR = __builtin_amdgcn_mfma_f32_16x16x32_bf16(prh, trl, sR, 0,0,0);
            sR = __builtin_amdgcn_mfma_f32_16x16x32_bf16(prl, trh, sR, 0,0,0);
            sR = __builtin_amdgcn_mfma_f32_16x16x32_bf16(pnh, tih, sR, 0,0,0);
            sR = __builtin_amdgcn_mfma_f32_16x16x32_bf16(pnh, til, sR, 0,0,0);
            sR = __builtin_amdgcn_mfma_f32_16x16x32_bf16(pnl, tih, sR, 0,0,0);
            sI = __builtin_amdgcn_mfma_f32_16x16x32_bf16(prh, tih, sI, 0,0,0);
            sI = __builtin_amdgcn_mfma_f32_16x16x32_bf16(prh, til, sI, 0,0,0);
            sI = __builtin_amdgcn_mfma_f32_16x16x32_bf16(prl, tih, sI, 0,0,0);
            sI = __builtin_amdgcn_mfma_f32_16x16x32_bf16(pih, trh, sI, 0,0,0);
            sI = __builtin_amdgcn_mfma_f32_16x16x32_bf16(pih, trl, sI, 0,0,0);
            sI = __builtin_amdgcn_mfma_f32_16x16x32_bf16(pil, trh, sI, 0,0,0);
        }
        // staged K-half reduction into S_s[qg*16 + c]  (S_s aliases dead Abuf)
        if (kh == 0){
            #pragma unroll
            for (int r = 0; r < 4; ++r)
                S_s[((size_t)qtile*16 + (lane>>4)*4 + r)*16 + lrow] =
                    make_float2(sR[r], sI[r]);
        }
        __syncthreads();
        if (kh == 1){
            #pragma unroll
            for (int r = 0; r < 4; ++r){
                const size_t si = ((size_t)qtile*16 + (lane>>4)*4 + r)*16 + lrow;
                float2 sp = S_s[si];
                sp.x += sR[r]; sp.y += sI[r];
                S_s[si] = sp;
            }
        }
        __syncthreads();
    }

    // ---- phase W: Vout[qr][d] = sum_{c,g} S[qr*4+g][c]*W[q][c][g][d]
    // + emit next layer's bf16 hi/lo operand at [arr][x][n=tid][k=i].
    if (tid < 256){
        const int qr2 = tid >> 4, d = tid & 15;
        const int q = P2R_c[qr2];
        float2 acc = make_float2(0.f, 0.f);
        const float2* Wb = (const float2*)W_k + (size_t)q*16*4*16 + d;
        #pragma unroll 4
        for (int c = 0; c < 16; ++c){
            #pragma unroll
            for (int g = 0; g < 4; ++g){
                acc = cmadd(acc, S_s[((size_t)qr2*4 + g)*16 + c], Wb[(c*4 + g)*16]);
            }
        }
        ((float2*)Vout)[(size_t)xi*256 + tid] = acc;
        const size_t vo = ((size_t)x*256 + tid)*96 + i;
        unsigned short h;
        h = f2bf(acc.x); Vbf_out[0*VBF_ARR + vo] = h;
        Vbf_out[1*VBF_ARR + vo] = f2bf(acc.x - bf2f(h));
        h = f2bf(acc.y); Vbf_out[2*VBF_ARR + vo] = h;
        Vbf_out[3*VBF_ARR + vo] = f2bf(acc.y - bf2f(h));
    }
}

// unpack final packed V -> d_out (x,i,q,d,r,z), zeros at r >= DIMS[q]
__global__ void unpack_V_kernel(const float* __restrict__ Vp,
                                float* __restrict__ out){
    int idx = blockIdx.x*blockDim.x + threadIdx.x;
    if (idx >= XS*NP*4*16*7) return;
    int r  = idx % 7;
    int d  = (idx / 7) % 16;
    int q  = (idx / (7*16)) % 4;
    int xi = idx / (7*16*4);
    float2 v = make_float2(0.f, 0.f);
    if (r < DIMS_c[q]){
        v = ((const float2*)Vp)[(size_t)xi*256 + (OFF_c[q] + r)*16 + d];
    }
    ((float2*)out)[idx] = v;
}

extern "C" void kernel_launch(void* const* d_in, const int* in_sizes, int n_in,
                              void* d_out, int out_size, void* d_ws, size_t ws_size,
                              hipStream_t stream) {
    const float* X  = (const float*)d_in[0];
    // d_in[1] is 'l' (always 3, hardcoded)
    const float* V  = (const float*)d_in[2];
    const float* cg = (const float*)d_in[3];
    const float* f  = (const float*)d_in[4];
    const float* W  = (const float*)d_in[5];
    // d_in[6] is C4 (plain complex product, hardcoded)

    // ws layout (floats): cgf 4704 | PKbf 49152 | Vout 98304 |
    // VbfA 98304 | VbfB 98304 | filt_g 1769472
    float* ws    = (float*)d_ws;
    float* cgf   = ws;
    unsigned short* PKbf = (unsigned short*)(ws + 4704);
    float* Vout  = ws + 4704 + 49152;
    unsigned short* VbfA = (unsigned short*)(ws + 4704 + 49152 + 98304);
    unsigned short* VbfB = (unsigned short*)(ws + 4704 + 49152 + 98304 + 98304);
    float* filt_g = ws + 4704 + 49152 + 98304 + 98304 + 98304;

    prep_kernel<<<(PREP_TOTAL + 255)/256, 256, 0, stream>>>(cg, f, V, cgf, PKbf, VbfA);
    filt_all_kernel<<<NLAY*NXI, 256, 0, stream>>>(X, cgf, filt_g);

    const float* W0 = W;
    const float* W1 = W + (size_t)1*4*16*4*16*2;
    const float* W2 = W + (size_t)2*4*16*4*16*2;
    const float* f0 = filt_g;
    const float* f1 = filt_g + (size_t)1*NXI*NP*16*2;
    const float* f2 = filt_g + (size_t)2*NXI*NP*16*2;

    TS_kernel<<<NXI, 512, 0, stream>>>(f0, PKbf, W0, VbfA, VbfB, Vout);
    TS_kernel<<<NXI, 512, 0, stream>>>(f1, PKbf, W1, VbfB, VbfA, Vout);
    TS_kernel<<<NXI, 512, 0, stream>>>(f2, PKbf, W2, VbfA, VbfB, Vout);

    unpack_V_kernel<<<(XS*NP*4*16*7 + 255)/256, 256, 0, stream>>>(Vout, (float*)d_out);
}

// Round 18
// 69.336 us; speedup vs baseline: 3.8758x; 1.0706x over previous
//
#include <hip/hip_runtime.h>
#include <hip/hip_bf16.h>

// Problem constants (shapes fixed by the reference)
#define XS   2
#define NP   96
#define NLAY 3
#define NXI  (XS*NP)   // 192
#define VBF_ARR (XS*256*96)   // 49152 ushorts per component array

// packed (rep,dim) index tables: 16 = 1+3+5+7 entries
__constant__ int P2R_c[16] = {0, 1,1,1, 2,2,2,2,2, 3,3,3,3,3,3,3};
__constant__ int P2D_c[16] = {0, 0,1,2, 0,1,2,3,4, 0,1,2,3,4,5,6};
__constant__ int DIMS_c[4] = {1,3,5,7};
__constant__ int OFF_c[4]  = {0,1,4,9};

typedef __attribute__((ext_vector_type(8))) short bf16x8;
typedef __attribute__((ext_vector_type(4))) float f32x4;

__device__ inline float2 cmadd(float2 acc, float2 a, float2 b){
    acc.x += a.x*b.x - a.y*b.y;
    acc.y += a.x*b.y + a.y*b.x;
    return acc;
}
__device__ inline unsigned short f2bf(float v){
    __hip_bfloat16 h = __float2bfloat16(v);
    union { __hip_bfloat16 h; unsigned short u; } cv; cv.h = h; return cv.u;
}
__device__ inline float bf2f(unsigned short u){
    union { unsigned short u; __hip_bfloat16 h; } cv; cv.u = u;
    return __bfloat162float(cv.h);
}

// Merged prep+filt kernel. Blocks [0,256): flat prep ranges
//   idx in [0,16384):  PKbf[6][qg][lm] bf16 hi/lo (S-phase A-operand)
//   idx in [16384,65536): Vbf0 pack: V -> bf16 hi/lo [arr][x][n=mtc][k=j]
// Blocks [256, 256+576): filters for (k, xi); cgf computed in-block (tiny).
__global__ __launch_bounds__(256)
void prep_filt_kernel(const float* __restrict__ cg,
                      const float* __restrict__ f,
                      const float* __restrict__ Vin,
                      const float* __restrict__ X,
                      unsigned short* __restrict__ PKbf,
                      unsigned short* __restrict__ Vbf0,
                      float* __restrict__ filt_g)      // [k][xi][96][16] complex
{
    __shared__ float2 cgf_s[784];
    __shared__ float2 dX_s[NP][7];

    const int tid = threadIdx.x;
    if (blockIdx.x < 256){
        int idx = blockIdx.x*256 + tid;
        if (idx < 16384){
            int id = idx;              // = qg*256 + lm
            int lm = id & 255;
            int qg = id >> 8;
            int ls = lm >> 4, mt = lm & 15;
            int qr = qg >> 2, g = qg & 3;
            int l = P2R_c[ls], s = P2D_c[ls];
            int m = P2R_c[mt], t = P2D_c[mt];
            int q = P2R_c[qr], r = P2D_c[qr];
            size_t co = (((((((size_t)g*4 + l)*7 + s)*4 + m)*7 + t)*4 + q)*7 + r);
            float re = cg[co*2], im = cg[co*2+1];
            unsigned short rh = f2bf(re), rl = f2bf(re - bf2f(rh));
            unsigned short ih = f2bf(im), il = f2bf(im - bf2f(ih));
            PKbf[0*16384 + id] = rh;
            PKbf[1*16384 + id] = rl;
            PKbf[2*16384 + id] = ih;
            PKbf[3*16384 + id] = il;
            PKbf[4*16384 + id] = ih ^ 0x8000;
            PKbf[5*16384 + id] = il ^ 0x8000;
        } else {
            int id = idx - 16384;      // = (x*256+n)*96 + kj
            int kj = id % 96;
            int n  = (id / 96) % 256;
            int x  = id / (96*256);
            int mt = n >> 4, c = n & 15;
            int m = P2R_c[mt], t = P2D_c[mt];
            const float* p = Vin + ((((size_t)(x*NP + kj)*4 + m)*16 + c)*7 + t)*2;
            float re = p[0], im = p[1];
            unsigned short h;
            h = f2bf(re); Vbf0[0*VBF_ARR + id] = h;
            Vbf0[1*VBF_ARR + id] = f2bf(re - bf2f(h));
            h = f2bf(im); Vbf0[2*VBF_ARR + id] = h;
            Vbf0[3*VBF_ARR + id] = f2bf(im - bf2f(h));
        }
        return;
    }

    // ---- filter blocks
    const int fb = blockIdx.x - 256;   // k*NXI + xi
    const int k  = fb / NXI;
    const int xi = fb % NXI;
    const int x = xi / NP, i = xi % NP;

    // compute cgf[k] in LDS (784 entries, 4 cmadd each)
    for (int u = tid; u < 784; u += 256){
        int qr = u / 49, st = u % 49;
        int s = st / 7, t = st % 7;
        int q = P2R_c[qr], r = P2D_c[qr];
        float2 acc = make_float2(0.f, 0.f);
        #pragma unroll
        for (int g = 0; g < 4; ++g){
            const float* cgp = cg + (((((((size_t)g*4+3)*7 + s)*4 + 3)*7 + t)*4 + q)*7 + r)*2;
            const float* fp  = f + ((k*4 + q)*4 + g)*2;
            acc = cmadd(acc, make_float2(cgp[0], cgp[1]), make_float2(fp[0], fp[1]));
        }
        cgf_s[u] = acc;
    }
    for (int e = tid; e < NP*7; e += 256){
        int j = e / 7, s = e % 7;
        const float* Xj = X + (((size_t)x*NP + j)*7 + s)*2;
        const float* Xi = X + (((size_t)x*NP + i)*7 + s)*2;
        dX_s[j][s] = make_float2(Xj[0]-Xi[0], Xj[1]-Xi[1]);
    }
    __syncthreads();

    float2* out = (float2*)filt_g + (size_t)fb*NP*16;
    for (int e = tid; e < NP*16; e += 256){
        int j = e >> 4, qr = e & 15;
        const float2* cb = cgf_s + qr*49;
        float2 acc = make_float2(0.f, 0.f);
        #pragma unroll
        for (int s = 0; s < 7; ++s){
            float2 inner = make_float2(0.f, 0.f);
            #pragma unroll
            for (int t = 0; t < 7; ++t)
                inner = cmadd(inner, cb[s*7 + t], dX_s[j][t]);
            acc = cmadd(acc, dX_s[j][s], inner);
        }
        if (qr >= 9){ float2 dv = dX_s[j][qr-9]; acc.x += dv.x; acc.y += dv.y; }
        out[e] = acc;
    }
}

// TS_kernel: one block per xi, 512 threads (8 waves). Both T and S on MFMA.
//  T: M16(ls) x K96(j) x N256(mtc) complex; A=filt (LDS), B=Vbf (global).
//  S: M64(qg) x K256(lm) x N16(c) complex; A=PKbf (global), B=T2buf (LDS).
//  W: VALU channel mix. LAST=0: emit next layer's Vbf operand.
//     LAST=1: write d_out directly (valid slots from (qr,d) threads; the 192
//     invalid r>=DIMS[q] slots zeroed by threads 256..447 - disjoint).
template<int LAST>
__global__ __launch_bounds__(512, 2)
void TS_kernel(const float* __restrict__ filt_gk,      // [xi][96][16] complex
               const unsigned short* __restrict__ PKbf,// [6][64][256] bf16
               const float* __restrict__ W_k,          // [q][c][g][d] complex
               const unsigned short* __restrict__ Vbf_in,  // [4][x][n][k] bf16
               unsigned short* __restrict__ Vbf_out,       // next layer (LAST=0)
               float* __restrict__ Dout)               // d_out (LAST=1)
{
    __shared__ __align__(16) unsigned short Abuf[6][16][104];  // 19968 B (aliased by S_s)
    __shared__ __align__(16) unsigned short T2buf[4][16][264]; // 33792 B
    float2* S_s = (float2*)&Abuf[0][0][0];                     // [qg][c] = 8192 B

    const int tid = threadIdx.x;
    const int xi = blockIdx.x;
    const int x = xi / NP, i = xi % NP;

    // build bf16 hi/lo A-operands from fp32 filters (L2-hot, 12 KB)
    for (int e = tid; e < NP*16; e += 512){
        const int j = e >> 4, ls = e & 15;
        float2 fv = ((const float2*)filt_gk)[((size_t)xi*NP + j)*16 + ls];
        unsigned short h = f2bf(fv.x);
        Abuf[0][ls][j] = h;
        Abuf[1][ls][j] = f2bf(fv.x - bf2f(h));
        h = f2bf(fv.y);
        unsigned short lo = f2bf(fv.y - bf2f(h));
        Abuf[2][ls][j] = h;
        Abuf[3][ls][j] = lo;
        Abuf[4][ls][j] = h  ^ 0x8000;   // -Fi (exact)
        Abuf[5][ls][j] = lo ^ 0x8000;
    }
    __syncthreads();

    const int w    = tid >> 6;
    const int lane = tid & 63;
    const int lrow = lane & 15;          // A row / B col / D col
    const int kb   = (lane >> 4) * 8;    // k sub-offset within K=32 step

    // ---- phase T (MFMA): T[ls][n] = sum_j F[j][ls]*V[j][n] (complex)
    {
        f32x4 accR[2], accI[2];
        #pragma unroll
        for (int nt = 0; nt < 2; ++nt){
            accR[nt] = (f32x4){0.f,0.f,0.f,0.f};
            accI[nt] = (f32x4){0.f,0.f,0.f,0.f};
        }
        const unsigned short* Vrh = Vbf_in + 0*VBF_ARR + (size_t)x*256*96;
        const unsigned short* Vrl = Vbf_in + 1*VBF_ARR + (size_t)x*256*96;
        const unsigned short* Vih = Vbf_in + 2*VBF_ARR + (size_t)x*256*96;
        const unsigned short* Vil = Vbf_in + 3*VBF_ARR + (size_t)x*256*96;
        #pragma unroll
        for (int kt = 0; kt < 3; ++kt){
            const int ka = kt*32 + kb;
            bf16x8 frh = *(const bf16x8*)&Abuf[0][lrow][ka];
            bf16x8 frl = *(const bf16x8*)&Abuf[1][lrow][ka];
            bf16x8 fih = *(const bf16x8*)&Abuf[2][lrow][ka];
            bf16x8 fil = *(const bf16x8*)&Abuf[3][lrow][ka];
            bf16x8 nfh = *(const bf16x8*)&Abuf[4][lrow][ka];
            bf16x8 nfl = *(const bf16x8*)&Abuf[5][lrow][ka];
            #pragma unroll
            for (int nt = 0; nt < 2; ++nt){
                const int n = w*32 + nt*16 + lrow;
                const size_t bo = (size_t)n*96 + ka;
                bf16x8 vrh = *(const bf16x8*)(Vrh + bo);
                bf16x8 vrl = *(const bf16x8*)(Vrl + bo);
                bf16x8 vih = *(const bf16x8*)(Vih + bo);
                bf16x8 vil = *(const bf16x8*)(Vil + bo);
                accR[nt] = __builtin_amdgcn_mfma_f32_16x16x32_bf16(frh, vrh, accR[nt], 0,0,0);
                accR[nt] = __builtin_amdgcn_mfma_f32_16x16x32_bf16(frh, vrl, accR[nt], 0,0,0);
                accR[nt] = __builtin_amdgcn_mfma_f32_16x16x32_bf16(frl, vrh, accR[nt], 0,0,0);
                accR[nt] = __builtin_amdgcn_mfma_f32_16x16x32_bf16(nfh, vih, accR[nt], 0,0,0);
                accR[nt] = __builtin_amdgcn_mfma_f32_16x16x32_bf16(nfh, vil, accR[nt], 0,0,0);
                accR[nt] = __builtin_amdgcn_mfma_f32_16x16x32_bf16(nfl, vih, accR[nt], 0,0,0);
                accI[nt] = __builtin_amdgcn_mfma_f32_16x16x32_bf16(frh, vih, accI[nt], 0,0,0);
                accI[nt] = __builtin_amdgcn_mfma_f32_16x16x32_bf16(frh, vil, accI[nt], 0,0,0);
                accI[nt] = __builtin_amdgcn_mfma_f32_16x16x32_bf16(frl, vih, accI[nt], 0,0,0);
                accI[nt] = __builtin_amdgcn_mfma_f32_16x16x32_bf16(fih, vrh, accI[nt], 0,0,0);
                accI[nt] = __builtin_amdgcn_mfma_f32_16x16x32_bf16(fih, vrl, accI[nt], 0,0,0);
                accI[nt] = __builtin_amdgcn_mfma_f32_16x16x32_bf16(fil, vrh, accI[nt], 0,0,0);
            }
        }
        // store straight to bf16 hi/lo B-operand: c = lrow, lm = ls*16 + mt
        #pragma unroll
        for (int nt = 0; nt < 2; ++nt){
            #pragma unroll
            for (int r = 0; r < 4; ++r){
                const int lmp = ((lane>>4)*4 + r)*16 + (w*2 + nt);
                float tr = accR[nt][r], ti = accI[nt][r];
                unsigned short h = f2bf(tr);
                T2buf[0][lrow][lmp] = h;
                T2buf[1][lrow][lmp] = f2bf(tr - bf2f(h));
                h = f2bf(ti);
                T2buf[2][lrow][lmp] = h;
                T2buf[3][lrow][lmp] = f2bf(ti - bf2f(h));
            }
        }
    }
    __syncthreads();

    // ---- phase S (MFMA): S[qg][c] = sum_lm PK^T[qg][lm] * T2[lm][c] (complex)
    {
        const int qtile = w & 3;
        const int kh    = w >> 2;
        f32x4 sR = (f32x4){0.f,0.f,0.f,0.f};
        f32x4 sI = (f32x4){0.f,0.f,0.f,0.f};
        #pragma unroll
        for (int kt4 = 0; kt4 < 4; ++kt4){
            const int kt = kh*4 + kt4;
            const int ka = kt*32 + kb;
            const size_t arow = (size_t)(qtile*16 + lrow)*256 + ka;
            bf16x8 prh = *(const bf16x8*)(PKbf + 0*16384 + arow);
            bf16x8 prl = *(const bf16x8*)(PKbf + 1*16384 + arow);
            bf16x8 pih = *(const bf16x8*)(PKbf + 2*16384 + arow);
            bf16x8 pil = *(const bf16x8*)(PKbf + 3*16384 + arow);
            bf16x8 pnh = *(const bf16x8*)(PKbf + 4*16384 + arow);
            bf16x8 pnl = *(const bf16x8*)(PKbf + 5*16384 + arow);
            bf16x8 trh = *(const bf16x8*)&T2buf[0][lrow][ka];
            bf16x8 trl = *(const bf16x8*)&T2buf[1][lrow][ka];
            bf16x8 tih = *(const bf16x8*)&T2buf[2][lrow][ka];
            bf16x8 til = *(const bf16x8*)&T2buf[3][lrow][ka];
            sR = __builtin_amdgcn_mfma_f32_16x16x32_bf16(prh, trh, sR, 0,0,0);
            sR = __builtin_amdgcn_mfma_f32_16x16x32_bf16(prh, trl, sR, 0,0,0);
            sR = __builtin_amdgcn_mfma_f32_16x16x32_bf16(prl, trh, sR, 0,0,0);
            sR = __builtin_amdgcn_mfma_f32_16x16x32_bf16(pnh, tih, sR, 0,0,0);
            sR = __builtin_amdgcn_mfma_f32_16x16x32_bf16(pnh, til, sR, 0,0,0);
            sR = __builtin_amdgcn_mfma_f32_16x16x32_bf16(pnl, tih, sR, 0,0,0);
            sI = __builtin_amdgcn_mfma_f32_16x16x32_bf16(prh, tih, sI, 0,0,0);
            sI = __builtin_amdgcn_mfma_f32_16x16x32_bf16(prh, til, sI, 0,0,0);
            sI = __builtin_amdgcn_mfma_f32_16x16x32_bf16(prl, tih, sI, 0,0,0);
            sI = __builtin_amdgcn_mfma_f32_16x16x32_bf16(pih, trh, sI, 0,0,0);
            sI = __builtin_amdgcn_mfma_f32_16x16x32_bf16(pih, trl, sI, 0,0,0);
            sI = __builtin_amdgcn_mfma_f32_16x16x32_bf16(pil, trh, sI, 0,0,0);
        }
        // staged K-half reduction into S_s[qg*16 + c]  (S_s aliases dead Abuf)
        if (kh == 0){
            #pragma unroll
            for (int r = 0; r < 4; ++r)
                S_s[((size_t)qtile*16 + (lane>>4)*4 + r)*16 + lrow] =
                    make_float2(sR[r], sI[r]);
        }
        __syncthreads();
        if (kh == 1){
            #pragma unroll
            for (int r = 0; r < 4; ++r){
                const size_t si = ((size_t)qtile*16 + (lane>>4)*4 + r)*16 + lrow;
                float2 sp = S_s[si];
                sp.x += sR[r]; sp.y += sI[r];
                S_s[si] = sp;
            }
        }
        __syncthreads();
    }

    // ---- phase W: out[qr][d] = sum_{c,g} S[qr*4+g][c]*W[q][c][g][d]
    if (tid < 256){
        const int qr2 = tid >> 4, d = tid & 15;
        const int q = P2R_c[qr2];
        float2 acc = make_float2(0.f, 0.f);
        const float2* Wb = (const float2*)W_k + (size_t)q*16*4*16 + d;
        #pragma unroll 4
        for (int c = 0; c < 16; ++c){
            #pragma unroll
            for (int g = 0; g < 4; ++g){
                acc = cmadd(acc, S_s[((size_t)qr2*4 + g)*16 + c], Wb[(c*4 + g)*16]);
            }
        }
        if (LAST){
            const int r = P2D_c[qr2];
            ((float2*)Dout)[((size_t)xi*4 + q)*112 + d*7 + r] = acc;
        } else {
            const size_t vo = ((size_t)x*256 + tid)*96 + i;
            unsigned short h;
            h = f2bf(acc.x); Vbf_out[0*VBF_ARR + vo] = h;
            Vbf_out[1*VBF_ARR + vo] = f2bf(acc.x - bf2f(h));
            h = f2bf(acc.y); Vbf_out[2*VBF_ARR + vo] = h;
            Vbf_out[3*VBF_ARR + vo] = f2bf(acc.y - bf2f(h));
        }
    } else if (LAST){
        // zero the 192 invalid (r >= DIMS[q]) slots; disjoint from valid writes
        const int u = tid - 256;
        if (u < 192){
            int q, base, span;
            if (u < 96)      { q = 0; base = 0;   span = 6; }
            else if (u < 160){ q = 1; base = 96;  span = 4; }
            else             { q = 2; base = 160; span = 2; }
            const int v = u - base;
            const int d = v / span;
            const int r = DIMS_c[q] + v % span;
            ((float2*)Dout)[((size_t)xi*4 + q)*112 + d*7 + r] = make_float2(0.f, 0.f);
        }
    }
}

extern "C" void kernel_launch(void* const* d_in, const int* in_sizes, int n_in,
                              void* d_out, int out_size, void* d_ws, size_t ws_size,
                              hipStream_t stream) {
    const float* X  = (const float*)d_in[0];
    // d_in[1] is 'l' (always 3, hardcoded)
    const float* V  = (const float*)d_in[2];
    const float* cg = (const float*)d_in[3];
    const float* f  = (const float*)d_in[4];
    const float* W  = (const float*)d_in[5];
    // d_in[6] is C4 (plain complex product, hardcoded)

    // ws layout (floats): PKbf 49152 | VbfA 98304 | VbfB 98304 | filt_g 1769472
    float* ws    = (float*)d_ws;
    unsigned short* PKbf = (unsigned short*)ws;
    unsigned short* VbfA = (unsigned short*)(ws + 49152);
    unsigned short* VbfB = (unsigned short*)(ws + 49152 + 98304);
    float* filt_g = ws + 49152 + 98304 + 98304;

    prep_filt_kernel<<<256 + NLAY*NXI, 256, 0, stream>>>(cg, f, V, X, PKbf, VbfA, filt_g);

    const float* W0 = W;
    const float* W1 = W + (size_t)1*4*16*4*16*2;
    const float* W2 = W + (size_t)2*4*16*4*16*2;
    const float* f0 = filt_g;
    const float* f1 = filt_g + (size_t)1*NXI*NP*16*2;
    const float* f2 = filt_g + (size_t)2*NXI*NP*16*2;

    TS_kernel<0><<<NXI, 512, 0, stream>>>(f0, PKbf, W0, VbfA, VbfB, nullptr);
    TS_kernel<0><<<NXI, 512, 0, stream>>>(f1, PKbf, W1, VbfB, VbfA, nullptr);
    TS_kernel<1><<<NXI, 512, 0, stream>>>(f2, PKbf, W2, VbfA, VbfB, (float*)d_out);
}